// Round 9
// baseline (145.434 us; speedup 1.0000x reference)
//
#include <hip/hip_runtime.h>
#include <math.h>

#define DET 512
#define NB  16
#define NT  180
#define PI_D 3.14159265358979323846
#define NPAIR 89
#define PADQ 108
#define NGP  45                  // interleaved pair-rows gp=0..44 (col gp | col 88-gp)
#define PKI_ROW 1536             // dwords per pair-row: 768 entries x 2 (T,U)
#define NUNIT 113                // live transpose-pair units (16x16 tiles, a<=b)

// ws layout (bytes):
//   [0,8192)       (unused)
//   [TT,+512K)     (unused; Toeplitz computed in-LDS by filter)
//   [XF0,+32K)     xf0[b][512]  f32   filtered row t=0
//   [XF90,+32K)    xf90[b][512] f32   filtered row t=90
//   [PK,+4.3M)     pki[b][gp][1536] u32  interleaved {T[i],U[i]} packed f16 pairs
#define TT_OFF   8192
#define XF0_OFF  (TT_OFF + 512*512*2)
#define XF90_OFF (XF0_OFF + 32768)
#define PK_OFF   (XF90_OFF + 32768)

typedef _Float16 half8  __attribute__((ext_vector_type(8)));
typedef _Float16 half4v __attribute__((ext_vector_type(4)));
typedef _Float16 half2v __attribute__((ext_vector_type(2)));
typedef float    float4v __attribute__((ext_vector_type(4)));

// f32 acc += f32 w * f16-half(pk)   (VOP3P mix, full-rate)
__device__ inline void fmix_lo(float& acc, float w, unsigned int pk) {
  asm("v_fma_mix_f32 %0, %1, %2, %0 op_sel_hi:[0,1,0]"
      : "+v"(acc) : "v"(w), "v"(pk));
}
__device__ inline void fmix_hi(float& acc, float w, unsigned int pk) {
  asm("v_fma_mix_f32 %0, %1, %2, %0 op_sel:[0,1,0] op_sel_hi:[0,1,0]"
      : "+v"(acc) : "v"(w), "v"(pk));
}

// ---------------- Filter (MFMA GEMM) + fused interleaved f16 pair-packing ----------------
// (R8 version, unchanged: Toeplitz B-operand from LDS shift-copies wls[8][1032].)
__global__ __launch_bounds__(256) void filter_kernel(const float* __restrict__ x,
                                                     char* __restrict__ wsb) {
  __shared__ _Float16 xs_h[16][512];
  __shared__ _Float16 xs_l[16][512];
  __shared__ float xfs[16][65];
  __shared__ _Float16 wls[8][1032];      // 8 shift-copies, 2064B row (16B-mult)
  unsigned int* pkg = (unsigned int*)(wsb + PK_OFF);

  int tid = threadIdx.x;
  int p = blockIdx.x, b = blockIdx.y;
  int dt0 = blockIdx.z * 2;

  // ---- fill Toeplitz shift-copies: thread fills 4 consecutive k for each r ----
  {
    int k0 = tid * 4;
    const float CSC = (float)(-2048.0 / (PI_D * PI_D));   // (w*1024) numerator
#pragma unroll
    for (int r = 0; r < 8; r++) {
      half4v v;
#pragma unroll
      for (int j = 0; j < 4; j++) {
        int delta = 511 - (k0 + j) - r;
        float wv;
        if (delta == 0) wv = 512.0f;                       // 0.5 * 1024
        else if (delta & 1) wv = CSC / (float)(delta * delta);
        else wv = 0.0f;
        v[j] = (_Float16)wv;
      }
      *(half4v*)&wls[r][k0] = v;
    }
  }

  int m = tid & 15, kp = tid >> 4;
  int tS;
  if (p < 11) tS = (m < 8) ? (8 * p + 1 + m) : (164 - 8 * p + m);
  else        tS = (m == 0) ? 89 : ((m == 1) ? 91 : ((m == 3) ? 90 : 0));
  const float* xb = x + (size_t)b * DET * NT + tS;
#pragma unroll 8
  for (int pass = 0; pass < 16; pass++) {
    int k = pass * 32 + kp * 2;
    int c = k >> 3, h = k & 7;
    int phys = (((c ^ (m & 7)) << 3) | h);
    float v0 = xb[(size_t)k * NT];
    float v1 = xb[(size_t)(k + 1) * NT];
    _Float16 h0 = (_Float16)v0, h1 = (_Float16)v1;
    half2v hh = {h0, h1};
    half2v ll = {(_Float16)(v0 - (float)h0), (_Float16)(v1 - (float)h1)};
    *(half2v*)&xs_h[m][phys] = hh;
    *(half2v*)&xs_l[m][phys] = ll;
  }
  __syncthreads();   // covers xs staging AND wls fill

  int nprb = (p < 11) ? 8 : 1;
  int tpb0 = (p < 11) ? 8 * p : 88;
  if (blockIdx.z == 0) {
    // zero pad entries [0,108) and [620,768) for both slots (uint2 per entry)
    int idx = (tid < 108) ? tid : (620 + (tid - 108));
    uint2 z2; z2.x = 0u; z2.y = 0u;
    for (int pr = 0; pr < nprb; pr++) {
      int tq = (p < 11) ? (tpb0 + pr) : 88;
      int gp = (tq <= 44) ? tq : 88 - tq;
      *(uint2*)&pkg[((size_t)b * NGP + gp) * PKI_ROW + 2 * idx] = z2;
    }
  }

  int lane = tid & 63, wv = tid >> 6;
  int mm = lane & 15, q = lane >> 4;
  const _Float16* arh = &xs_h[mm][0];
  const _Float16* arl = &xs_l[mm][0];
  int e = mm & 7;
  int mp = tid >> 5, cc = (tid & 31) * 2;
  int rT = (p < 11) ? mp : 0;
  int rU = (p < 11) ? (15 - mp) : 1;
  int tpp = (p < 11) ? (8 * p + mp) : 88;
  bool dopack = (p < 11) || (mp == 0);
  int gp_  = (tpp <= 44) ? tpp : 88 - tpp;
  int slot = (tpp <= 44) ? 0 : 1;

  for (int dti = 0; dti < 2; dti++) {
    int dt = dt0 + dti;
    int dw = dt * 64 + wv * 16 + mm;
    int sdw = 511 - dw;
    const _Float16* thl = &wls[sdw & 7][sdw & ~7];   // 16B-aligned per-lane base
    float4v acc0 = {0.f, 0.f, 0.f, 0.f};
    float4v acc1 = {0.f, 0.f, 0.f, 0.f};
#pragma unroll 4
    for (int kc = 0; kc < 512; kc += 32) {
      int ph = ((((kc >> 3) + q) ^ e) << 3);
      half8 Ah = *(const half8*)&arh[ph];
      half8 Al = *(const half8*)&arl[ph];
      half8 Bh = *(const half8*)&thl[kc + q * 8];
      acc0 = __builtin_amdgcn_mfma_f32_16x16x32_f16(Ah, Bh, acc0, 0, 0, 0);
      acc1 = __builtin_amdgcn_mfma_f32_16x16x32_f16(Al, Bh, acc1, 0, 0, 0);
    }
    if (dti > 0) __syncthreads();
#pragma unroll
    for (int i = 0; i < 4; i++)
      xfs[q * 4 + i][wv * 16 + mm] = (acc0[i] + acc1[i]) * 0.0009765625f;
    __syncthreads();
    if (dopack) {
      float ft0 = xfs[rT][cc], ft1 = xfs[rT][cc + 1];
      float fu0 = xfs[rU][cc], fu1 = xfs[rU][cc + 1];
      auto p0 = __builtin_amdgcn_cvt_pkrtz(ft0, fu0);   // lo=ft, hi=fu
      auto p1 = __builtin_amdgcn_cvt_pkrtz(ft1, fu1);
      unsigned int w0, w1;
      __builtin_memcpy(&w0, &p0, 4);
      __builtin_memcpy(&w1, &p1, 4);
      unsigned int* row = pkg + ((size_t)b * NGP + gp_) * PKI_ROW;
      int en = PADQ + dt * 64 + cc;
      row[2 * en + slot]     = w0;
      row[2 * en + 2 + slot] = w1;
      if (tpp == 44) {               // self-paired row: duplicate into slot 1
        row[2 * en + 1] = w0;
        row[2 * en + 3] = w1;
      }
    }
    if (p == 11 && tid < 64) {         // singles: row2=t0, row3=t90
      float* f0  = (float*)(wsb + XF0_OFF)  + (size_t)b * DET;
      float* f90 = (float*)(wsb + XF90_OFF) + (size_t)b * DET;
      f0[dt * 64 + tid]  = xfs[2][tid];
      f90[dt * 64 + tid] = xfs[3][tid];
    }
  }
}

// ---------------- Backprojection v15: batch-paired units ----------------
// Two batches b0,b0+1 share identical geometry (tile, iy, taps, LDS addresses).
// One block handles both: support ops (iy/fract/addr) computed ONCE, fmix set
// applied twice against two staged rows. Support VALU per unit ~halved; barrier
// count halved (912x45 vs 1824x45); LDS 24.6KB but resident demand only
// ~3.6 blocks/CU -> waves/CU unchanged (14.25). Arithmetic order per output
// identical to v12r -> absmax must stay bit-identical.
#define RDFMIX(colX, rr, SW)                                                   \
  {                                                                            \
    uint4 rA, rB, rMA, rMB;                                                    \
    __builtin_memcpy(&rA,  &colX[2 * iA], 16);                                 \
    __builtin_memcpy(&rB,  &colX[2 * iB], 16);                                 \
    __builtin_memcpy(&rMA, &colX[2 * (726 - iA)], 16);                         \
    __builtin_memcpy(&rMB, &colX[2 * (726 - iB)], 16);                         \
    unsigned tA0 = SW ? rA.y : rA.x,  tA1 = SW ? rA.w : rA.z;                  \
    unsigned uA0 = SW ? rA.x : rA.y,  uA1 = SW ? rA.z : rA.w;                  \
    unsigned tB0 = SW ? rB.y : rB.x,  tB1 = SW ? rB.w : rB.z;                  \
    unsigned uB0 = SW ? rB.x : rB.y,  uB1 = SW ? rB.z : rB.w;                  \
    unsigned tMA0 = SW ? rMA.y : rMA.x,  tMA1 = SW ? rMA.w : rMA.z;            \
    unsigned uMA0 = SW ? rMA.x : rMA.y,  uMA1 = SW ? rMA.z : rMA.w;            \
    unsigned tMB0 = SW ? rMB.y : rMB.x,  tMB1 = SW ? rMB.w : rMB.z;            \
    unsigned uMB0 = SW ? rMB.x : rMB.y,  uMB1 = SW ? rMB.z : rMB.w;            \
    fmix_lo(A1[rr], vA, tA0);  fmix_lo(A1[rr], wA, tA1);                       \
    fmix_hi(A1[rr], vB, tB0);  fmix_hi(A1[rr], wB, tB1);                       \
    fmix_lo(A2[rr], vB, tB0);  fmix_lo(A2[rr], wB, tB1);                       \
    fmix_hi(A2[rr], vA, tA0);  fmix_hi(A2[rr], wA, tA1);                       \
    fmix_lo(A3[rr], wA, tMA0); fmix_lo(A3[rr], vA, tMA1);                      \
    fmix_hi(A3[rr], wB, tMB0); fmix_hi(A3[rr], vB, tMB1);                      \
    fmix_lo(A4[rr], wB, tMB0); fmix_lo(A4[rr], vB, tMB1);                      \
    fmix_hi(A4[rr], wA, tMA0); fmix_hi(A4[rr], vA, tMA1);                      \
    if (doQ) {                                                                 \
      fmix_lo(B1[rr], wA, uMA0); fmix_lo(B1[rr], vA, uMA1);                    \
      fmix_hi(B1[rr], vB, uB0);  fmix_hi(B1[rr], wB, uB1);                     \
      fmix_lo(B2[rr], wB, uMB0); fmix_lo(B2[rr], vB, uMB1);                    \
      fmix_hi(B2[rr], vA, uA0);  fmix_hi(B2[rr], wA, uA1);                     \
      fmix_lo(B3[rr], vA, uA0);  fmix_lo(B3[rr], wA, uA1);                     \
      fmix_hi(B3[rr], wB, uMB0); fmix_hi(B3[rr], vB, uMB1);                    \
      fmix_lo(B4[rr], vB, uB0);  fmix_lo(B4[rr], wB, uB1);                     \
      fmix_hi(B4[rr], wA, uMA0); fmix_hi(B4[rr], vA, uMA1);                    \
    }                                                                          \
  }

#define PROCESS(c_, s_, SW)                                                    \
  {                                                                            \
    float inner = fmaf(-(s_), q_, 363.5f);                                     \
    float iyA = fmaf( (c_), p_, inner);                                        \
    float iyB = fmaf(-(c_), p_, inner);                                        \
    int   iA = (int)iyA;  float wA = __builtin_amdgcn_fractf(iyA);             \
    int   iB = (int)iyB;  float wB = __builtin_amdgcn_fractf(iyB);             \
    float vA = 1.f - wA, vB = 1.f - wB;                                        \
    RDFMIX(colI0, 0, SW)                                                       \
    RDFMIX(colI1, 1, SW)                                                       \
  }

__global__ __launch_bounds__(256, 4) void backproj_kernel(
    const char* __restrict__ wsb, float* __restrict__ out) {
  __shared__ unsigned int pk[2][2][PKI_ROW];   // 24576 B: [par][b-half][row]
  __shared__ float2 trigs[48];
  int tid = threadIdx.x;
  int b0  = blockIdx.y * 2;
  int bx  = blockIdx.x;
  int lx = tid & 15, ly = tid >> 4;
  float* ob0 = out + (size_t)b0 * DET * DET;
  float* ob1 = out + (size_t)(b0 + 1) * DET * DET;

  if (bx == NUNIT) {
    // zero dead 16x16 tiles (a, bt<L[a]) and their 3 mirrors, both batches
    const int LDEAD[10] = {10,8,6,5,4,3,2,2,1,1};
    for (int a = 0; a < 10; a++)
      for (int bt = 0; bt < LDEAD[a]; bt++) {
        int X1 = 16*a + lx, X2 = 511 - X1;
        int Y1 = 16*bt + ly, Y2 = 511 - Y1;
        ob0[(size_t)Y1*DET + X1] = 0.f;  ob1[(size_t)Y1*DET + X1] = 0.f;
        ob0[(size_t)Y1*DET + X2] = 0.f;  ob1[(size_t)Y1*DET + X2] = 0.f;
        ob0[(size_t)Y2*DET + X1] = 0.f;  ob1[(size_t)Y2*DET + X1] = 0.f;
        ob0[(size_t)Y2*DET + X2] = 0.f;  ob1[(size_t)Y2*DET + X2] = 0.f;
      }
    return;
  }

  // unit decode: a via cumulative table, bt = bx - S[a] + bstart[a]
  int a = (bx>=6)+(bx>=14)+(bx>=24)+(bx>=35)+(bx>=47)+(bx>=58)+(bx>=68)
        + (bx>=77)+(bx>=85)+(bx>=92)+(bx>=98)+(bx>=103)+(bx>=107)+(bx>=110)+(bx>=112);
  int Sa, bs;
  if (a < 8) { Sa = (int)((0x443A2F23180E0600ULL >> (8*a)) & 0xFF);
               bs = (int)((0x070605040506080AULL >> (8*a)) & 0xFF); }
  else       { Sa = (int)((0x706E6B67625C554DULL >> (8*(a-8))) & 0xFF);
               bs = (int)((0x0F0E0D0C0B0A0908ULL >> (8*(a-8))) & 0xFF); }
  int bt = bx - Sa + bs;
  bool doQ = (a != bt);
  int tx = 16*a, ty = 16*bt;

  int X1 = tx + lx, X2 = 511 - X1;
  int Y1 = ty + ly, Y2 = 511 - Y1;
  float p_ = (float)X1 - 255.5f;
  float q_ = (float)Y1 - 255.5f;

  int w = tid >> 6, l = tid & 63;
  int mkx = 481 - 32*a;
  int mky = 505 - 32*bt - 8*w;          // min |ky| over this wave's 4 rows
  bool wlive = (mkx*mkx + mky*mky <= 261632);   // symmetric: covers P and Q sets

  // pair trig (ct - cu)/2 = cos t, (st + su)/2 = sin t for u = 180 - t
  if (tid < NGP) {
    float th = (float)(tid + 1) * (float)(PI_D / 180.0);
    float2 cs; cs.x = cosf(th); cs.y = sinf(th);
    trigs[tid] = cs;
  }

  const unsigned int* pkg0 = (const unsigned int*)(wsb + PK_OFF) + (size_t)b0 * NGP * PKI_ROW;
  const unsigned int* pkg1 = pkg0 + (size_t)NGP * PKI_ROW;

  float A1[2]={0,0}, A2[2]={0,0}, A3[2]={0,0}, A4[2]={0,0};
  float B1[2]={0,0}, B2[2]={0,0}, B3[2]={0,0}, B4[2]={0,0};

  // stage pair-rows (b0,g) and (b1,g): 12 chunks of 1024B over 4 waves
  // (16B/lane DMA, 3 chunks/wave uniform)
  auto stage_group = [&](int g, int par) {
#pragma unroll
    for (int i = 0; i < 3; i++) {
      int c = w + 4 * i;                 // 0..11
      int r = (c < 6) ? 0 : 1;
      int off = (c < 6) ? c : (c - 6);
      const unsigned int* src = (r ? pkg1 : pkg0) + (size_t)g * PKI_ROW + off * 256 + l * 4;
      char* dst = (char*)&pk[par][r][0] + off * 1024;
      __builtin_amdgcn_global_load_lds(
          (const __attribute__((address_space(1))) unsigned int*)src,
          (__attribute__((address_space(3))) unsigned int*)dst, 16, 0, 0);
    }
  };

  stage_group(0, 0);
  __syncthreads();   // covers stage(0) AND trigs fill

  for (int g = 0; g < NGP; g++) {
    if (g + 1 < NGP) stage_group(g + 1, (g + 1) & 1);
    float2 cs = trigs[g];
    const unsigned int* colI0 = &pk[g & 1][0][0];
    const unsigned int* colI1 = &pk[g & 1][1][0];
    if (wlive) {
      PROCESS(cs.x, cs.y, 0);                    // tp = g      (P=slot0, Q=slot1)
      if (g != 44) PROCESS(cs.y, cs.x, 1);       // tp = 88-g   (P=slot1, Q=slot0)
    }
    __syncthreads();
  }

  // epilogue: singles t=0 / t=90, mask, scale — per batch
  const float SC = (float)(PI_D / 360.0);
  int kx = 2*X1 - 511, ky = 2*Y1 - 511;
  bool in = (kx*kx + ky*ky) <= 261632;            // symmetric across all 8 outputs

  float Qs[2][4];
#pragma unroll
  for (int rr = 0; rr < 2; rr++) {
    const float* f0  = (const float*)(wsb + XF0_OFF)  + (size_t)(b0 + rr) * DET;
    const float* f90 = (const float*)(wsb + XF90_OFF) + (size_t)(b0 + rr) * DET;
    float* ob = rr ? ob1 : ob0;
    float g0x1 = f0[X1], g0x2 = f0[X2];
    float g90y1 = f90[Y1], g90y2 = f90[Y2];
    float P1 = A1[rr] + g0x1 + g90y2;
    float P2 = A2[rr] + g0x2 + g90y2;
    float P3 = A3[rr] + g0x2 + g90y1;
    float P4 = A4[rr] + g0x1 + g90y1;
    ob[(size_t)Y1*DET + X1] = in ? P1*SC : 0.f;
    ob[(size_t)Y1*DET + X2] = in ? P2*SC : 0.f;
    ob[(size_t)Y2*DET + X2] = in ? P3*SC : 0.f;
    ob[(size_t)Y2*DET + X1] = in ? P4*SC : 0.f;
    if (doQ) {
      float g0y1 = f0[Y1], g0y2 = f0[Y2];
      float g90x1 = f90[X1], g90x2 = f90[X2];
      Qs[rr][0] = in ? (B1[rr] + g0y1 + g90x2) * SC : 0.f;
      Qs[rr][1] = in ? (B2[rr] + g0y1 + g90x1) * SC : 0.f;
      Qs[rr][2] = in ? (B3[rr] + g0y2 + g90x1) * SC : 0.f;
      Qs[rr][3] = in ? (B4[rr] + g0y2 + g90x2) * SC : 0.f;
    }
  }

  if (doQ) {
    __syncthreads();                                // pk free now
    float* qs0 = (float*)&pk[0][0][0];              // [4][16][17] padded
    float* qs1 = (float*)&pk[0][1][0];
#pragma unroll
    for (int i = 0; i < 4; i++) {
      qs0[(i*16 + lx)*17 + ly] = Qs[0][i];
      qs1[(i*16 + lx)*17 + ly] = Qs[1][i];
    }
    __syncthreads();
    int r1 = tx + ly, r2 = 511 - r1;
    int c1 = ty + lx, c2 = 511 - c1;
#pragma unroll
    for (int rr = 0; rr < 2; rr++) {
      float* qs = rr ? qs1 : qs0;
      float* ob = rr ? ob1 : ob0;
      float o1 = qs[(0*16 + ly)*17 + lx];
      float o2 = qs[(1*16 + ly)*17 + lx];
      float o3 = qs[(2*16 + ly)*17 + lx];
      float o4 = qs[(3*16 + ly)*17 + lx];
      ob[(size_t)r1*DET + c1] = o1;   // Q1: rows X1, cols Y1
      ob[(size_t)r2*DET + c1] = o2;   // Q2: rows X2, cols Y1
      ob[(size_t)r2*DET + c2] = o3;   // Q3: rows X2, cols Y2
      ob[(size_t)r1*DET + c2] = o4;   // Q4: rows X1, cols Y2
    }
  }
}

extern "C" void kernel_launch(void* const* d_in, const int* in_sizes, int n_in,
                              void* d_out, int out_size, void* d_ws, size_t ws_size,
                              hipStream_t stream) {
  (void)in_sizes; (void)n_in; (void)out_size; (void)ws_size;
  const float* x = (const float*)d_in[0];
  float* out = (float*)d_out;
  char*  wsb = (char*)d_ws;

  filter_kernel<<<dim3(12, 16, 4), 256, 0, stream>>>(x, wsb);
  backproj_kernel<<<dim3(NUNIT + 1, NB / 2), 256, 0, stream>>>(wsb, out);
}

// Round 10
// 139.243 us; speedup vs baseline: 1.0445x; 1.0445x over previous
//
#include <hip/hip_runtime.h>
#include <math.h>

#define DET 512
#define NB  16
#define NT  180
#define PI_D 3.14159265358979323846
#define NPAIR 89
#define PADQ 108
#define NGP  45                  // interleaved pair-rows gp=0..44 (col gp | col 88-gp)
#define PKI_ROW 1536             // dwords per pair-row: 768 entries x 2 (T,U)
#define NOFF 101                 // off-diagonal transpose-pair units (a < bt)
#define NMRG 6                   // merged-diagonal blocks (2 diagonals each, a=4..15)
#define NBX  108                 // 101 off-diag + 6 merged-diag + 1 zeroer

// ws layout (bytes):
//   [0,8192)       (unused)
//   [TT,+512K)     (unused; Toeplitz computed in-LDS by filter)
//   [XF0,+32K)     xf0[b][512]  f32   filtered row t=0
//   [XF90,+32K)    xf90[b][512] f32   filtered row t=90
//   [PK,+4.3M)     pki[b][gp][1536] u32  interleaved {T[i],U[i]} packed f16 pairs
#define TT_OFF   8192
#define XF0_OFF  (TT_OFF + 512*512*2)
#define XF90_OFF (XF0_OFF + 32768)
#define PK_OFF   (XF90_OFF + 32768)

typedef _Float16 half8  __attribute__((ext_vector_type(8)));
typedef _Float16 half4v __attribute__((ext_vector_type(4)));
typedef _Float16 half2v __attribute__((ext_vector_type(2)));
typedef float    float4v __attribute__((ext_vector_type(4)));

// f32 acc += f32 w * f16-half(pk)   (VOP3P mix, full-rate)
__device__ inline void fmix_lo(float& acc, float w, unsigned int pk) {
  asm("v_fma_mix_f32 %0, %1, %2, %0 op_sel_hi:[0,1,0]"
      : "+v"(acc) : "v"(w), "v"(pk));
}
__device__ inline void fmix_hi(float& acc, float w, unsigned int pk) {
  asm("v_fma_mix_f32 %0, %1, %2, %0 op_sel:[0,1,0] op_sel_hi:[0,1,0]"
      : "+v"(acc) : "v"(w), "v"(pk));
}

// ---------------- Filter (MFMA GEMM) + fused interleaved f16 pair-packing ----------------
// (R8 version, unchanged: Toeplitz B-operand from LDS shift-copies wls[8][1032].)
__global__ __launch_bounds__(256) void filter_kernel(const float* __restrict__ x,
                                                     char* __restrict__ wsb) {
  __shared__ _Float16 xs_h[16][512];
  __shared__ _Float16 xs_l[16][512];
  __shared__ float xfs[16][65];
  __shared__ _Float16 wls[8][1032];      // 8 shift-copies, 2064B row (16B-mult)
  unsigned int* pkg = (unsigned int*)(wsb + PK_OFF);

  int tid = threadIdx.x;
  int p = blockIdx.x, b = blockIdx.y;
  int dt0 = blockIdx.z * 2;

  // ---- fill Toeplitz shift-copies: thread fills 4 consecutive k for each r ----
  {
    int k0 = tid * 4;
    const float CSC = (float)(-2048.0 / (PI_D * PI_D));   // (w*1024) numerator
#pragma unroll
    for (int r = 0; r < 8; r++) {
      half4v v;
#pragma unroll
      for (int j = 0; j < 4; j++) {
        int delta = 511 - (k0 + j) - r;
        float wv;
        if (delta == 0) wv = 512.0f;                       // 0.5 * 1024
        else if (delta & 1) wv = CSC / (float)(delta * delta);
        else wv = 0.0f;
        v[j] = (_Float16)wv;
      }
      *(half4v*)&wls[r][k0] = v;
    }
  }

  int m = tid & 15, kp = tid >> 4;
  int tS;
  if (p < 11) tS = (m < 8) ? (8 * p + 1 + m) : (164 - 8 * p + m);
  else        tS = (m == 0) ? 89 : ((m == 1) ? 91 : ((m == 3) ? 90 : 0));
  const float* xb = x + (size_t)b * DET * NT + tS;
#pragma unroll 8
  for (int pass = 0; pass < 16; pass++) {
    int k = pass * 32 + kp * 2;
    int c = k >> 3, h = k & 7;
    int phys = (((c ^ (m & 7)) << 3) | h);
    float v0 = xb[(size_t)k * NT];
    float v1 = xb[(size_t)(k + 1) * NT];
    _Float16 h0 = (_Float16)v0, h1 = (_Float16)v1;
    half2v hh = {h0, h1};
    half2v ll = {(_Float16)(v0 - (float)h0), (_Float16)(v1 - (float)h1)};
    *(half2v*)&xs_h[m][phys] = hh;
    *(half2v*)&xs_l[m][phys] = ll;
  }
  __syncthreads();   // covers xs staging AND wls fill

  int nprb = (p < 11) ? 8 : 1;
  int tpb0 = (p < 11) ? 8 * p : 88;
  if (blockIdx.z == 0) {
    // zero pad entries [0,108) and [620,768) for both slots (uint2 per entry)
    int idx = (tid < 108) ? tid : (620 + (tid - 108));
    uint2 z2; z2.x = 0u; z2.y = 0u;
    for (int pr = 0; pr < nprb; pr++) {
      int tq = (p < 11) ? (tpb0 + pr) : 88;
      int gp = (tq <= 44) ? tq : 88 - tq;
      *(uint2*)&pkg[((size_t)b * NGP + gp) * PKI_ROW + 2 * idx] = z2;
    }
  }

  int lane = tid & 63, wv = tid >> 6;
  int mm = lane & 15, q = lane >> 4;
  const _Float16* arh = &xs_h[mm][0];
  const _Float16* arl = &xs_l[mm][0];
  int e = mm & 7;
  int mp = tid >> 5, cc = (tid & 31) * 2;
  int rT = (p < 11) ? mp : 0;
  int rU = (p < 11) ? (15 - mp) : 1;
  int tpp = (p < 11) ? (8 * p + mp) : 88;
  bool dopack = (p < 11) || (mp == 0);
  int gp_  = (tpp <= 44) ? tpp : 88 - tpp;
  int slot = (tpp <= 44) ? 0 : 1;

  for (int dti = 0; dti < 2; dti++) {
    int dt = dt0 + dti;
    int dw = dt * 64 + wv * 16 + mm;
    int sdw = 511 - dw;
    const _Float16* thl = &wls[sdw & 7][sdw & ~7];   // 16B-aligned per-lane base
    float4v acc0 = {0.f, 0.f, 0.f, 0.f};
    float4v acc1 = {0.f, 0.f, 0.f, 0.f};
#pragma unroll 4
    for (int kc = 0; kc < 512; kc += 32) {
      int ph = ((((kc >> 3) + q) ^ e) << 3);
      half8 Ah = *(const half8*)&arh[ph];
      half8 Al = *(const half8*)&arl[ph];
      half8 Bh = *(const half8*)&thl[kc + q * 8];
      acc0 = __builtin_amdgcn_mfma_f32_16x16x32_f16(Ah, Bh, acc0, 0, 0, 0);
      acc1 = __builtin_amdgcn_mfma_f32_16x16x32_f16(Al, Bh, acc1, 0, 0, 0);
    }
    if (dti > 0) __syncthreads();
#pragma unroll
    for (int i = 0; i < 4; i++)
      xfs[q * 4 + i][wv * 16 + mm] = (acc0[i] + acc1[i]) * 0.0009765625f;
    __syncthreads();
    if (dopack) {
      float ft0 = xfs[rT][cc], ft1 = xfs[rT][cc + 1];
      float fu0 = xfs[rU][cc], fu1 = xfs[rU][cc + 1];
      auto p0 = __builtin_amdgcn_cvt_pkrtz(ft0, fu0);   // lo=ft, hi=fu
      auto p1 = __builtin_amdgcn_cvt_pkrtz(ft1, fu1);
      unsigned int w0, w1;
      __builtin_memcpy(&w0, &p0, 4);
      __builtin_memcpy(&w1, &p1, 4);
      unsigned int* row = pkg + ((size_t)b * NGP + gp_) * PKI_ROW;
      int en = PADQ + dt * 64 + cc;
      row[2 * en + slot]     = w0;
      row[2 * en + 2 + slot] = w1;
      if (tpp == 44) {               // self-paired row: duplicate into slot 1
        row[2 * en + 1] = w0;
        row[2 * en + 3] = w1;
      }
    }
    if (p == 11 && tid < 64) {         // singles: row2=t0, row3=t90
      float* f0  = (float*)(wsb + XF0_OFF)  + (size_t)b * DET;
      float* f90 = (float*)(wsb + XF90_OFF) + (size_t)b * DET;
      f0[dt * 64 + tid]  = xfs[2][tid];
      f90[dt * 64 + tid] = xfs[3][tid];
    }
  }
}

// ---------------- Backprojection v16: uniform-weight blocks ----------------
// R8-v12r core (82.3 µs measured) with load balancing: the 12 half-weight
// diagonal units (a==bt, no Q) are merged pairwise into 6 full-weight blocks
// that process two diagonals against the SAME staged columns. The 101 off-diag
// blocks drop the doQ conditional (always true). Grid 108x16 = 1728 uniform
// blocks (6.75/CU, makespan 7 units vs ~7.4 mixed). Per-pixel arithmetic
// identical -> absmax must stay bit-identical.

// off-diag process: P-quad + Q-quad, shared tap reads
#define PROCESS(c_, s_, SW)                                                    \
  {                                                                            \
    float inner = fmaf(-(s_), q_, 363.5f);                                     \
    float iyA = fmaf( (c_), p_, inner);                                        \
    float iyB = fmaf(-(c_), p_, inner);                                        \
    int   iA = (int)iyA;  float wA = __builtin_amdgcn_fractf(iyA);             \
    int   iB = (int)iyB;  float wB = __builtin_amdgcn_fractf(iyB);             \
    float vA = 1.f - wA, vB = 1.f - wB;                                        \
    uint4 rA, rB, rMA, rMB;                                                    \
    __builtin_memcpy(&rA,  &colI[2 * iA], 16);                                 \
    __builtin_memcpy(&rB,  &colI[2 * iB], 16);                                 \
    __builtin_memcpy(&rMA, &colI[2 * (726 - iA)], 16);                         \
    __builtin_memcpy(&rMB, &colI[2 * (726 - iB)], 16);                         \
    unsigned tA0 = SW ? rA.y : rA.x,  tA1 = SW ? rA.w : rA.z;                  \
    unsigned uA0 = SW ? rA.x : rA.y,  uA1 = SW ? rA.z : rA.w;                  \
    unsigned tB0 = SW ? rB.y : rB.x,  tB1 = SW ? rB.w : rB.z;                  \
    unsigned uB0 = SW ? rB.x : rB.y,  uB1 = SW ? rB.z : rB.w;                  \
    unsigned tMA0 = SW ? rMA.y : rMA.x,  tMA1 = SW ? rMA.w : rMA.z;            \
    unsigned uMA0 = SW ? rMA.x : rMA.y,  uMA1 = SW ? rMA.z : rMA.w;            \
    unsigned tMB0 = SW ? rMB.y : rMB.x,  tMB1 = SW ? rMB.w : rMB.z;            \
    unsigned uMB0 = SW ? rMB.x : rMB.y,  uMB1 = SW ? rMB.z : rMB.w;            \
    fmix_lo(A1, vA, tA0);  fmix_lo(A1, wA, tA1);                               \
    fmix_hi(A1, vB, tB0);  fmix_hi(A1, wB, tB1);                               \
    fmix_lo(A2, vB, tB0);  fmix_lo(A2, wB, tB1);                               \
    fmix_hi(A2, vA, tA0);  fmix_hi(A2, wA, tA1);                               \
    fmix_lo(A3, wA, tMA0); fmix_lo(A3, vA, tMA1);                              \
    fmix_hi(A3, wB, tMB0); fmix_hi(A3, vB, tMB1);                              \
    fmix_lo(A4, wB, tMB0); fmix_lo(A4, vB, tMB1);                              \
    fmix_hi(A4, wA, tMA0); fmix_hi(A4, vA, tMA1);                              \
    fmix_lo(B1, wA, uMA0); fmix_lo(B1, vA, uMA1);                              \
    fmix_hi(B1, vB, uB0);  fmix_hi(B1, wB, uB1);                               \
    fmix_lo(B2, wB, uMB0); fmix_lo(B2, vB, uMB1);                              \
    fmix_hi(B2, vA, uA0);  fmix_hi(B2, wA, uA1);                               \
    fmix_lo(B3, vA, uA0);  fmix_lo(B3, wA, uA1);                               \
    fmix_hi(B3, wB, uMB0); fmix_hi(B3, vB, uMB1);                              \
    fmix_lo(B4, vB, uB0);  fmix_lo(B4, wB, uB1);                               \
    fmix_hi(B4, wA, uMA0); fmix_hi(B4, vA, uMA1);                              \
  }

// diagonal process: P-quad only, parameterized pixel context + accumulators
#define PROCESSP(c_, s_, SW, pp, qq, AA1, AA2, AA3, AA4)                       \
  {                                                                            \
    float inner = fmaf(-(s_), (qq), 363.5f);                                   \
    float iyA = fmaf( (c_), (pp), inner);                                      \
    float iyB = fmaf(-(c_), (pp), inner);                                      \
    int   iA = (int)iyA;  float wA = __builtin_amdgcn_fractf(iyA);             \
    int   iB = (int)iyB;  float wB = __builtin_amdgcn_fractf(iyB);             \
    float vA = 1.f - wA, vB = 1.f - wB;                                        \
    uint4 rA, rB, rMA, rMB;                                                    \
    __builtin_memcpy(&rA,  &colI[2 * iA], 16);                                 \
    __builtin_memcpy(&rB,  &colI[2 * iB], 16);                                 \
    __builtin_memcpy(&rMA, &colI[2 * (726 - iA)], 16);                         \
    __builtin_memcpy(&rMB, &colI[2 * (726 - iB)], 16);                         \
    unsigned tA0 = SW ? rA.y : rA.x,  tA1 = SW ? rA.w : rA.z;                  \
    unsigned tB0 = SW ? rB.y : rB.x,  tB1 = SW ? rB.w : rB.z;                  \
    unsigned tMA0 = SW ? rMA.y : rMA.x,  tMA1 = SW ? rMA.w : rMA.z;            \
    unsigned tMB0 = SW ? rMB.y : rMB.x,  tMB1 = SW ? rMB.w : rMB.z;            \
    fmix_lo(AA1, vA, tA0);  fmix_lo(AA1, wA, tA1);                             \
    fmix_hi(AA1, vB, tB0);  fmix_hi(AA1, wB, tB1);                             \
    fmix_lo(AA2, vB, tB0);  fmix_lo(AA2, wB, tB1);                             \
    fmix_hi(AA2, vA, tA0);  fmix_hi(AA2, wA, tA1);                             \
    fmix_lo(AA3, wA, tMA0); fmix_lo(AA3, vA, tMA1);                            \
    fmix_hi(AA3, wB, tMB0); fmix_hi(AA3, vB, tMB1);                            \
    fmix_lo(AA4, wB, tMB0); fmix_lo(AA4, vB, tMB1);                            \
    fmix_hi(AA4, wA, tMA0); fmix_hi(AA4, vA, tMA1);                            \
  }

__global__ __launch_bounds__(256, 8) void backproj_kernel(
    const char* __restrict__ wsb, float* __restrict__ out) {
  __shared__ unsigned int pk[2][PKI_ROW];   // 12288 B; epilogue-aliased as qs
  __shared__ float2 trigs[48];
  int tid = threadIdx.x;
  int b   = blockIdx.y;
  int bx  = blockIdx.x;
  int lx = tid & 15, ly = tid >> 4;
  float* ob = out + (size_t)b * DET * DET;
  int w = tid >> 6, l = tid & 63;

  if (bx == NOFF + NMRG) {
    // zero dead 16x16 tiles (a, bt<L[a]) and their 3 mirrors
    const int LDEAD[10] = {10,8,6,5,4,3,2,2,1,1};
    for (int a = 0; a < 10; a++)
      for (int bt = 0; bt < LDEAD[a]; bt++) {
        int X1 = 16*a + lx, X2 = 511 - X1;
        int Y1 = 16*bt + ly, Y2 = 511 - Y1;
        ob[(size_t)Y1*DET + X1] = 0.f;
        ob[(size_t)Y1*DET + X2] = 0.f;
        ob[(size_t)Y2*DET + X1] = 0.f;
        ob[(size_t)Y2*DET + X2] = 0.f;
      }
    return;
  }

  // pair trig: (cos t, sin t), t = tid+1 degrees
  if (tid < NGP) {
    float th = (float)(tid + 1) * (float)(PI_D / 180.0);
    float2 cs; cs.x = cosf(th); cs.y = sinf(th);
    trigs[tid] = cs;
  }

  const unsigned int* pkg = (const unsigned int*)(wsb + PK_OFF) + (size_t)b * NGP * PKI_ROW;

  // stage pair-row gp (6144 B): 6 chunks of 1024B over 4 waves (16B/lane DMA)
  auto stage_group = [&](int g, int par) {
    {
      const unsigned int* src = pkg + (size_t)g * PKI_ROW + w * 256 + l * 4;
      char* dst = (char*)&pk[par][0] + w * 1024;
      __builtin_amdgcn_global_load_lds(
          (const __attribute__((address_space(1))) unsigned int*)src,
          (__attribute__((address_space(3))) unsigned int*)dst, 16, 0, 0);
    }
    if (w < 2) {
      const unsigned int* src = pkg + (size_t)g * PKI_ROW + (w + 4) * 256 + l * 4;
      char* dst = (char*)&pk[par][0] + (w + 4) * 1024;
      __builtin_amdgcn_global_load_lds(
          (const __attribute__((address_space(1))) unsigned int*)src,
          (__attribute__((address_space(3))) unsigned int*)dst, 16, 0, 0);
    }
  };

  const float* f0  = (const float*)(wsb + XF0_OFF)  + (size_t)b * DET;
  const float* f90 = (const float*)(wsb + XF90_OFF) + (size_t)b * DET;
  const float SC = (float)(PI_D / 360.0);

  if (bx >= NOFF) {
    // ---- merged-diagonal block: two diagonal tiles (a1,a1),(a2,a2), P-only ----
    int d = bx - NOFF;
    int a1 = 4 + 2 * d, a2 = 5 + 2 * d;
    float p1_ = (float)(16 * a1 + lx) - 255.5f, q1_ = (float)(16 * a1 + ly) - 255.5f;
    float p2_ = (float)(16 * a2 + lx) - 255.5f, q2_ = (float)(16 * a2 + ly) - 255.5f;
    int mk1 = 481 - 32 * a1, mn1 = 505 - 32 * a1 - 8 * w;
    int mk2 = 481 - 32 * a2, mn2 = 505 - 32 * a2 - 8 * w;
    bool wl1 = (mk1 * mk1 + mn1 * mn1 <= 261632);
    bool wl2 = (mk2 * mk2 + mn2 * mn2 <= 261632);

    float A1=0.f, A2=0.f, A3=0.f, A4=0.f;   // tile a1
    float C1=0.f, C2=0.f, C3=0.f, C4=0.f;   // tile a2

    stage_group(0, 0);
    __syncthreads();
    for (int g = 0; g < NGP; g++) {
      if (g + 1 < NGP) stage_group(g + 1, (g + 1) & 1);
      float2 cs = trigs[g];
      const unsigned int* colI = &pk[g & 1][0];
      if (wl1) {
        PROCESSP(cs.x, cs.y, 0, p1_, q1_, A1, A2, A3, A4);
        if (g != 44) PROCESSP(cs.y, cs.x, 1, p1_, q1_, A1, A2, A3, A4);
      }
      if (wl2) {
        PROCESSP(cs.x, cs.y, 0, p2_, q2_, C1, C2, C3, C4);
        if (g != 44) PROCESSP(cs.y, cs.x, 1, p2_, q2_, C1, C2, C3, C4);
      }
      __syncthreads();
    }
#pragma unroll
    for (int t = 0; t < 2; t++) {
      int a = t ? a2 : a1;
      int X1 = 16 * a + lx, X2 = 511 - X1;
      int Y1 = 16 * a + ly, Y2 = 511 - Y1;
      int kx = 2 * X1 - 511, ky = 2 * Y1 - 511;
      bool in = (kx * kx + ky * ky) <= 261632;
      float g0x1 = f0[X1], g0x2 = f0[X2];
      float g90y1 = f90[Y1], g90y2 = f90[Y2];
      float P1 = (t ? C1 : A1) + g0x1 + g90y2;
      float P2 = (t ? C2 : A2) + g0x2 + g90y2;
      float P3 = (t ? C3 : A3) + g0x2 + g90y1;
      float P4 = (t ? C4 : A4) + g0x1 + g90y1;
      ob[(size_t)Y1 * DET + X1] = in ? P1 * SC : 0.f;
      ob[(size_t)Y1 * DET + X2] = in ? P2 * SC : 0.f;
      ob[(size_t)Y2 * DET + X2] = in ? P3 * SC : 0.f;
      ob[(size_t)Y2 * DET + X1] = in ? P4 * SC : 0.f;
    }
    return;
  }

  // ---- off-diagonal unit (a < bt): P-quad + transposed Q-quad ----
  // a via cumulative off-diag table S'={0,6,14,24,35,46,56,65,73,80,86,91,95,98,100}
  int a = (bx>=6)+(bx>=14)+(bx>=24)+(bx>=35)+(bx>=46)+(bx>=56)+(bx>=65)
        + (bx>=73)+(bx>=80)+(bx>=86)+(bx>=91)+(bx>=95)+(bx>=98)+(bx>=100);
  int Sa, bs;
  if (a < 8) { Sa = (int)((0x41382E23180E0600ULL >> (8*a)) & 0xFF);
               bs = (int)((0x080706050506080AULL >> (8*a)) & 0xFF); }
  else       { Sa = (int)((0x0064625F5B565049ULL >> (8*(a-8))) & 0xFF);
               bs = (int)((0x000F0E0D0C0B0A09ULL >> (8*(a-8))) & 0xFF); }
  int bt = bx - Sa + bs;
  int tx = 16*a, ty = 16*bt;

  int X1 = tx + lx, X2 = 511 - X1;
  int Y1 = ty + ly, Y2 = 511 - Y1;
  float p_ = (float)X1 - 255.5f;
  float q_ = (float)Y1 - 255.5f;

  int mkx = 481 - 32*a;
  int mky = 505 - 32*bt - 8*w;          // min |ky| over this wave's 4 rows
  bool wlive = (mkx*mkx + mky*mky <= 261632);   // symmetric: covers P and Q sets

  float A1=0.f, A2=0.f, A3=0.f, A4=0.f;   // P-tile mirrors
  float B1=0.f, B2=0.f, B3=0.f, B4=0.f;   // Q (transposed) tile mirrors

  stage_group(0, 0);
  __syncthreads();   // covers stage(0) AND trigs fill

  for (int g = 0; g < NGP; g++) {
    if (g + 1 < NGP) stage_group(g + 1, (g + 1) & 1);
    float2 cs = trigs[g];
    const unsigned int* colI = &pk[g & 1][0];
    if (wlive) {
      PROCESS(cs.x, cs.y, 0);                    // tp = g      (P=slot0, Q=slot1)
      if (g != 44) PROCESS(cs.y, cs.x, 1);       // tp = 88-g   (P=slot1, Q=slot0)
    }
    __syncthreads();
  }

  // epilogue: singles t=0 / t=90, mask, scale
  int kx = 2*X1 - 511, ky = 2*Y1 - 511;
  bool in = (kx*kx + ky*ky) <= 261632;            // symmetric across all 8 outputs

  float g0x1 = f0[X1], g0x2 = f0[X2];
  float g90y1 = f90[Y1], g90y2 = f90[Y2];
  float P1 = A1 + g0x1 + g90y2;
  float P2 = A2 + g0x2 + g90y2;
  float P3 = A3 + g0x2 + g90y1;
  float P4 = A4 + g0x1 + g90y1;
  ob[(size_t)Y1*DET + X1] = in ? P1*SC : 0.f;
  ob[(size_t)Y1*DET + X2] = in ? P2*SC : 0.f;
  ob[(size_t)Y2*DET + X2] = in ? P3*SC : 0.f;
  ob[(size_t)Y2*DET + X1] = in ? P4*SC : 0.f;

  {
    float g0y1 = f0[Y1], g0y2 = f0[Y2];
    float g90x1 = f90[X1], g90x2 = f90[X2];
    float Q1 = B1 + g0y1 + g90x2;
    float Q2 = B2 + g0y1 + g90x1;
    float Q3 = B3 + g0y2 + g90x1;
    float Q4 = B4 + g0y2 + g90x2;
    Q1 = in ? Q1*SC : 0.f;
    Q2 = in ? Q2*SC : 0.f;
    Q3 = in ? Q3*SC : 0.f;
    Q4 = in ? Q4*SC : 0.f;
    __syncthreads();                                // pk free now
    float* qs = (float*)&pk[0][0];                  // [4][16][17] padded
    qs[(0*16 + lx)*17 + ly] = Q1;
    qs[(1*16 + lx)*17 + ly] = Q2;
    qs[(2*16 + lx)*17 + ly] = Q3;
    qs[(3*16 + lx)*17 + ly] = Q4;
    __syncthreads();
    float o1 = qs[(0*16 + ly)*17 + lx];
    float o2 = qs[(1*16 + ly)*17 + lx];
    float o3 = qs[(2*16 + ly)*17 + lx];
    float o4 = qs[(3*16 + ly)*17 + lx];
    int r1 = tx + ly, r2 = 511 - r1;
    int c1 = ty + lx, c2 = 511 - c1;
    ob[(size_t)r1*DET + c1] = o1;   // Q1: rows X1, cols Y1
    ob[(size_t)r2*DET + c1] = o2;   // Q2: rows X2, cols Y1
    ob[(size_t)r2*DET + c2] = o3;   // Q3: rows X2, cols Y2
    ob[(size_t)r1*DET + c2] = o4;   // Q4: rows X1, cols Y2
  }
}

extern "C" void kernel_launch(void* const* d_in, const int* in_sizes, int n_in,
                              void* d_out, int out_size, void* d_ws, size_t ws_size,
                              hipStream_t stream) {
  (void)in_sizes; (void)n_in; (void)out_size; (void)ws_size;
  const float* x = (const float*)d_in[0];
  float* out = (float*)d_out;
  char*  wsb = (char*)d_ws;

  filter_kernel<<<dim3(12, 16, 4), 256, 0, stream>>>(x, wsb);
  backproj_kernel<<<dim3(NBX, NB), 256, 0, stream>>>(wsb, out);
}